// Round 2
// baseline (3072.047 us; speedup 1.0000x reference)
//
#include <hip/hip_runtime.h>

#define NN 100000
#define NE 3200000
#define D  128

// --- 0. detect edge_index element width: int64 -> odd int32 slots (high words) all zero ---
__global__ void detect_kernel(const int* __restrict__ ei, int* __restrict__ flag) {
    int t = threadIdx.x;
    int v = ei[2 * t + 1];                 // int64: high word (=0); int32: a real index
    unsigned long long ball = __ballot(v != 0);
    if (t == 0) flag[0] = (ball == 0ull) ? 1 : 0;   // 1 => int64
}

// --- 1. weighted in-degree over dst ---
__global__ void deg_kernel(const int* __restrict__ ei, const float* __restrict__ ew,
                           float* __restrict__ deg, const int* __restrict__ flag) {
    int s = flag[0];
    int e = blockIdx.x * 256 + threadIdx.x;
    if (e < NE) {
        int dst = ei[(NE + e) << s];
        atomicAdd(&deg[dst], ew[e]);
    }
}

// --- 2. dis = rsqrt(1 + deg)   (self-loop weight 1 folded in; 1+deg > 0 always) ---
__global__ void dis_kernel(float* __restrict__ deg) {
    int n = blockIdx.x * 256 + threadIdx.x;
    if (n < NN) deg[n] = rsqrtf(1.0f + deg[n]);
}

// --- 3. acc[n][d] = x[n][d] * dis[n]^2   (self-loop message; also initializes acc) ---
__global__ void acc_init_kernel(const float2* __restrict__ x2, const float* __restrict__ dis,
                                float2* __restrict__ acc2) {
    int i = blockIdx.x * 256 + threadIdx.x;   // over NN*64 float2
    if (i < NN * 64) {
        int n = i >> 6;
        float s = dis[n]; s *= s;
        float2 v = x2[i];
        v.x *= s; v.y *= s;
        acc2[i] = v;
    }
}

// --- 4. push-scatter: one wave per edge, 2 dims per lane, fp32 atomics ---
__global__ void scatter_kernel(const int* __restrict__ ei, const float* __restrict__ ew,
                               const float* __restrict__ dis, const float2* __restrict__ x2,
                               float* __restrict__ acc, const int* __restrict__ flag) {
    int s = flag[0];
    int t = blockIdx.x * 256 + threadIdx.x;
    int e = t >> 6, l = t & 63;
    if (e < NE) {
        int src = ei[e << s];
        int dst = ei[(NE + e) << s];
        float nrm = dis[src] * ew[e] * dis[dst];
        float2 v = x2[src * 64 + l];
        float* p = acc + dst * D + l * 2;
        atomicAdd(p,     v.x * nrm);
        atomicAdd(p + 1, v.y * nrm);
    }
}

// --- 5. out = acc @ W + b ; 16 rows/block, 256 threads, 8 cols/thread, fp32 ---
__global__ __launch_bounds__(256) void gemm_kernel(const float* __restrict__ acc,
        const float* __restrict__ W, const float* __restrict__ bias,
        float* __restrict__ out) {
    __shared__ float A[16][D + 1];
    int t = threadIdx.x;
    long base = (long)blockIdx.x * 16;
    const float4* Ag = (const float4*)(acc + base * D);
#pragma unroll
    for (int i = 0; i < 2; i++) {
        int idx = t + 256 * i;          // 512 float4 = 16 rows x 128 f32
        float4 v = Ag[idx];
        int r = idx >> 5, c = (idx & 31) << 2;
        A[r][c] = v.x; A[r][c + 1] = v.y; A[r][c + 2] = v.z; A[r][c + 3] = v.w;
    }
    __syncthreads();
    int r = t >> 4, cg = t & 15;
    float c[8];
#pragma unroll
    for (int j = 0; j < 8; j++) c[j] = 0.f;
    const float4* W4 = (const float4*)W;   // row k: 32 float4; thread uses 2 at cg*2
#pragma unroll 4
    for (int k = 0; k < D; k++) {
        float a = A[r][k];
        float4 w0 = W4[k * 32 + cg * 2];
        float4 w1 = W4[k * 32 + cg * 2 + 1];
        c[0] += a * w0.x; c[1] += a * w0.y; c[2] += a * w0.z; c[3] += a * w0.w;
        c[4] += a * w1.x; c[5] += a * w1.y; c[6] += a * w1.z; c[7] += a * w1.w;
    }
    long row = base + r;
    float4 o0, o1;
    const float* bp = bias + cg * 8;
    o0.x = c[0] + bp[0]; o0.y = c[1] + bp[1]; o0.z = c[2] + bp[2]; o0.w = c[3] + bp[3];
    o1.x = c[4] + bp[4]; o1.y = c[5] + bp[5]; o1.z = c[6] + bp[6]; o1.w = c[7] + bp[7];
    float4* op = (float4*)(out + row * D) + cg * 2;
    op[0] = o0; op[1] = o1;
}

extern "C" void kernel_launch(void* const* d_in, const int* in_sizes, int n_in,
                              void* d_out, int out_size, void* d_ws, size_t ws_size,
                              hipStream_t stream) {
    const float* x  = (const float*)d_in[0];    // fp32 [NN,128]
    const int*   ei = (const int*)d_in[1];      // [2,NE] int32 (or int64 -> detected)
    const float* ew = (const float*)d_in[2];    // fp32 [NE]
    const float* W  = (const float*)d_in[3];    // fp32 [128,128]
    const float* b  = (const float*)d_in[4];    // fp32 [128]
    float* out = (float*)d_out;                 // fp32 [NN,128]

    float* acc  = (float*)d_ws;                 // NN*128 f32 = 51.2 MB
    float* deg  = acc + (size_t)NN * D;         // NN f32 (becomes dis in-place)
    int*   flag = (int*)(deg + NN);             // 1 int

    detect_kernel<<<1, 64, 0, stream>>>(ei, flag);
    hipMemsetAsync(deg, 0, NN * sizeof(float), stream);
    deg_kernel<<<(NE + 255) / 256, 256, 0, stream>>>(ei, ew, deg, flag);
    dis_kernel<<<(NN + 255) / 256, 256, 0, stream>>>(deg);
    acc_init_kernel<<<(NN * 64) / 256, 256, 0, stream>>>((const float2*)x, deg, (float2*)acc);
    scatter_kernel<<<(int)(((long)NE * 64) / 256), 256, 0, stream>>>(ei, ew, deg, (const float2*)x, acc, flag);
    gemm_kernel<<<NN / 16, 256, 0, stream>>>(acc, W, b, out);
}

// Round 3
// 1194.922 us; speedup vs baseline: 2.5709x; 2.5709x over previous
//
#include <hip/hip_runtime.h>

#define NN 100000
#define NE 3200000
#define D  128

// --- 0. detect edge_index element width: int64 -> odd int32 slots (high words) all zero ---
__global__ void detect_kernel(const int* __restrict__ ei, int* __restrict__ flag) {
    int t = threadIdx.x;
    int v = ei[2 * t + 1];                 // int64: high word (=0); int32: a real index
    unsigned long long ball = __ballot(v != 0);
    if (t == 0) flag[0] = (ball == 0ull) ? 1 : 0;   // 1 => int64
}

// --- 1. weighted in-degree + edge count per dst ---
__global__ void hist_kernel(const int* __restrict__ ei, const float* __restrict__ ew,
                            float* __restrict__ deg, int* __restrict__ cnt,
                            const int* __restrict__ flag) {
    int s = flag[0];
    int e = blockIdx.x * 256 + threadIdx.x;
    if (e < NE) {
        int dst = ei[(NE + e) << s];
        atomicAdd(&deg[dst], ew[e]);
        atomicAdd(&cnt[dst], 1);
    }
}

// --- 2. dis = rsqrt(1 + deg)   (self-loop weight 1 folded in; 1+deg > 0 always) ---
__global__ void dis_kernel(float* __restrict__ deg) {
    int n = blockIdx.x * 256 + threadIdx.x;
    if (n < NN) deg[n] = rsqrtf(1.0f + deg[n]);
}

// --- 3. exclusive scan of cnt -> row_ptr[NN+1], and a second copy for bucket fill ---
__global__ __launch_bounds__(1024) void scan_kernel(const int* __restrict__ cnt,
                                                    int* __restrict__ row_ptr,
                                                    int* __restrict__ fill) {
    __shared__ int part[1024];
    int t = threadIdx.x;
    const int CH = (NN + 1023) / 1024;     // 98
    int beg = t * CH, end = beg + CH; if (end > NN) end = NN; if (beg > NN) beg = NN;
    int s = 0;
    for (int i = beg; i < end; i++) s += cnt[i];
    part[t] = s;
    __syncthreads();
    for (int off = 1; off < 1024; off <<= 1) {
        int v = (t >= off) ? part[t - off] : 0;
        __syncthreads();
        part[t] += v;
        __syncthreads();
    }
    int run = (t > 0) ? part[t - 1] : 0;   // exclusive base for this chunk
    for (int i = beg; i < end; i++) {
        row_ptr[i] = run; fill[i] = run;
        run += cnt[i];
    }
    if (t == 1023) row_ptr[NN] = part[1023];   // == NE
}

// --- 4. bucket fill: csr[pos] = (src, norm) for each edge, grouped by dst ---
__global__ void fill_kernel(const int* __restrict__ ei, const float* __restrict__ ew,
                            const float* __restrict__ dis, int* __restrict__ fill,
                            int2* __restrict__ csr, const int* __restrict__ flag) {
    int s = flag[0];
    int e = blockIdx.x * 256 + threadIdx.x;
    if (e < NE) {
        int src = ei[e << s];
        int dst = ei[(NE + e) << s];
        int pos = atomicAdd(&fill[dst], 1);
        float nrm = dis[src] * ew[e] * dis[dst];
        int2 c; c.x = src; c.y = __float_as_int(nrm);
        csr[pos] = c;
    }
}

// --- 5. pull aggregation: one wave per node, 2 dims per lane, no float atomics ---
__global__ __launch_bounds__(256) void pull_kernel(const float2* __restrict__ x2,
        const float* __restrict__ dis, const int* __restrict__ row_ptr,
        const int2* __restrict__ csr, float2* __restrict__ out2) {
    int t = blockIdx.x * 256 + threadIdx.x;
    int n = t >> 6, l = t & 63;
    if (n >= NN) return;
    float s = dis[n]; float ss = s * s;
    float2 a = x2[n * 64 + l];
    float accx = a.x * ss, accy = a.y * ss;      // self-loop term
    int beg = row_ptr[n], end = row_ptr[n + 1];
    int e = beg;
    for (; e + 1 < end; e += 2) {                // 2-edge unroll for MLP
        int2 c0 = csr[e], c1 = csr[e + 1];
        float2 v0 = x2[c0.x * 64 + l];
        float2 v1 = x2[c1.x * 64 + l];
        float n0 = __int_as_float(c0.y), n1 = __int_as_float(c1.y);
        accx += v0.x * n0; accy += v0.y * n0;
        accx += v1.x * n1; accy += v1.y * n1;
    }
    if (e < end) {
        int2 c0 = csr[e];
        float2 v0 = x2[c0.x * 64 + l];
        float n0 = __int_as_float(c0.y);
        accx += v0.x * n0; accy += v0.y * n0;
    }
    float2 r; r.x = accx; r.y = accy;
    out2[n * 64 + l] = r;
}

// --- 6. out = out @ W + b  IN-PLACE; 16 rows/block staged in LDS first ---
__global__ __launch_bounds__(256) void gemm_kernel(float* __restrict__ io,
        const float* __restrict__ W, const float* __restrict__ bias) {
    __shared__ float A[16][D + 1];
    int t = threadIdx.x;
    long base = (long)blockIdx.x * 16;
    const float4* Ag = (const float4*)(io + base * D);
#pragma unroll
    for (int i = 0; i < 2; i++) {
        int idx = t + 256 * i;          // 512 float4 = 16 rows x 128 f32
        float4 v = Ag[idx];
        int r = idx >> 5, c = (idx & 31) << 2;
        A[r][c] = v.x; A[r][c + 1] = v.y; A[r][c + 2] = v.z; A[r][c + 3] = v.w;
    }
    __syncthreads();
    int r = t >> 4, cg = t & 15;
    float c[8];
#pragma unroll
    for (int j = 0; j < 8; j++) c[j] = 0.f;
    const float4* W4 = (const float4*)W;
#pragma unroll 4
    for (int k = 0; k < D; k++) {
        float a = A[r][k];
        float4 w0 = W4[k * 32 + cg * 2];
        float4 w1 = W4[k * 32 + cg * 2 + 1];
        c[0] += a * w0.x; c[1] += a * w0.y; c[2] += a * w0.z; c[3] += a * w0.w;
        c[4] += a * w1.x; c[5] += a * w1.y; c[6] += a * w1.z; c[7] += a * w1.w;
    }
    long row = base + r;
    float4 o0, o1;
    const float* bp = bias + cg * 8;
    o0.x = c[0] + bp[0]; o0.y = c[1] + bp[1]; o0.z = c[2] + bp[2]; o0.w = c[3] + bp[3];
    o1.x = c[4] + bp[4]; o1.y = c[5] + bp[5]; o1.z = c[6] + bp[6]; o1.w = c[7] + bp[7];
    float4* op = (float4*)(io + row * D) + cg * 2;
    op[0] = o0; op[1] = o1;
}

extern "C" void kernel_launch(void* const* d_in, const int* in_sizes, int n_in,
                              void* d_out, int out_size, void* d_ws, size_t ws_size,
                              hipStream_t stream) {
    const float* x  = (const float*)d_in[0];    // fp32 [NN,128]
    const int*   ei = (const int*)d_in[1];      // [2,NE] int32 (or int64 -> detected)
    const float* ew = (const float*)d_in[2];    // fp32 [NE]
    const float* W  = (const float*)d_in[3];    // fp32 [128,128]
    const float* b  = (const float*)d_in[4];    // fp32 [128]
    float* out = (float*)d_out;                 // fp32 [NN,128]

    // workspace layout (~27 MB)
    float* deg     = (float*)d_ws;              // NN f32 (becomes dis in-place)
    int*   cnt     = (int*)(deg + NN);          // NN
    int*   row_ptr = cnt + NN;                  // NN+1
    int*   fill    = row_ptr + NN + 1;          // NN
    int*   flag    = fill + NN;                 // 1
    int2*  csr     = (int2*)(((uintptr_t)(flag + 1) + 15) & ~(uintptr_t)15); // NE int2

    detect_kernel<<<1, 64, 0, stream>>>(ei, flag);
    hipMemsetAsync(deg, 0, 2 * NN * sizeof(int), stream);   // zeros deg + cnt
    hist_kernel<<<(NE + 255) / 256, 256, 0, stream>>>(ei, ew, deg, cnt, flag);
    dis_kernel<<<(NN + 255) / 256, 256, 0, stream>>>(deg);
    scan_kernel<<<1, 1024, 0, stream>>>(cnt, row_ptr, fill);
    fill_kernel<<<(NE + 255) / 256, 256, 0, stream>>>(ei, ew, deg, fill, csr, flag);
    pull_kernel<<<(NN * 64) / 256, 256, 0, stream>>>((const float2*)x, deg, row_ptr, csr, (float2*)out);
    gemm_kernel<<<NN / 16, 256, 0, stream>>>(out, W, b);
}

// Round 4
// 1054.208 us; speedup vs baseline: 2.9141x; 1.1335x over previous
//
#include <hip/hip_runtime.h>

#define NN 100000
#define NE 3200000
#define D  128

__device__ __forceinline__ float bf2f(unsigned int u) {      // u = bf16 bits
    union { unsigned int i; float f; } v; v.i = u << 16; return v.f;
}
__device__ __forceinline__ unsigned int f2bf(float f) {      // RNE
    union { float f; unsigned int i; } v; v.f = f;
    unsigned int u = v.i;
    return (u + 0x7fffu + ((u >> 16) & 1u)) >> 16;
}

// --- 0. detect edge_index element width: int64 -> odd int32 slots (high words) all zero ---
__global__ void detect_kernel(const int* __restrict__ ei, int* __restrict__ flag) {
    int t = threadIdx.x;
    int v = ei[2 * t + 1];
    unsigned long long ball = __ballot(v != 0);
    if (t == 0) flag[0] = (ball == 0ull) ? 1 : 0;   // 1 => int64
}

// --- 1. x -> packed bf16x2 copy (halves gather bytes in pull) ---
__global__ void xhalf_kernel(const float2* __restrict__ x2, unsigned int* __restrict__ xh) {
    int i = blockIdx.x * 256 + threadIdx.x;          // NN*64 exactly
    float2 v = x2[i];
    xh[i] = f2bf(v.x) | (f2bf(v.y) << 16);
}

// --- 2. edge count per dst (int atomics only; weighted degree comes later, atomic-free) ---
__global__ void hist_kernel(const int* __restrict__ ei, int* __restrict__ cnt,
                            const int* __restrict__ flag) {
    int s = flag[0];
    int e = blockIdx.x * 256 + threadIdx.x;
    if (e < NE) atomicAdd(&cnt[ei[(NE + e) << s]], 1);
}

// --- 3. exclusive scan of cnt -> row_ptr[NN+1] + fill cursor copy ---
__global__ __launch_bounds__(1024) void scan_kernel(const int* __restrict__ cnt,
                                                    int* __restrict__ row_ptr,
                                                    int* __restrict__ fill) {
    __shared__ int part[1024];
    int t = threadIdx.x;
    const int CH = (NN + 1023) / 1024;
    int beg = t * CH, end = beg + CH; if (end > NN) end = NN; if (beg > NN) beg = NN;
    int s = 0;
    for (int i = beg; i < end; i++) s += cnt[i];
    part[t] = s;
    __syncthreads();
    for (int off = 1; off < 1024; off <<= 1) {
        int v = (t >= off) ? part[t - off] : 0;
        __syncthreads();
        part[t] += v;
        __syncthreads();
    }
    int run = (t > 0) ? part[t - 1] : 0;
    for (int i = beg; i < end; i++) {
        row_ptr[i] = run; fill[i] = run;
        run += cnt[i];
    }
    if (t == 1023) row_ptr[NN] = part[1023];
}

// --- 4. bucket fill: csr[pos] = src(17b) | ew_bf16_unsigned(15b) -- one 4B scattered store ---
__global__ void fill_kernel(const int* __restrict__ ei, const float* __restrict__ ew,
                            int* __restrict__ fill, unsigned int* __restrict__ csr,
                            const int* __restrict__ flag) {
    int s = flag[0];
    int e = blockIdx.x * 256 + threadIdx.x;
    if (e < NE) {
        int src = ei[e << s];
        int dst = ei[(NE + e) << s];
        int pos = atomicAdd(&fill[dst], 1);
        unsigned int wb = f2bf(ew[e]);               // ew >= 0: sign bit is 0
        csr[pos] = ((unsigned int)src << 15) | (wb >> 1);
    }
}

// --- 5. dis[n] = rsqrt(1 + sum_row ew) -- coalesced, atomic-free; one wave per node ---
__global__ __launch_bounds__(256) void disr_kernel(const int* __restrict__ row_ptr,
        const unsigned int* __restrict__ csr, float* __restrict__ dis) {
    int n = blockIdx.x * 4 + (threadIdx.x >> 6);
    int l = threadIdx.x & 63;
    int beg = row_ptr[n], end = row_ptr[n + 1];
    float s = 0.f;
    for (int e = beg + l; e < end; e += 64)
        s += bf2f((csr[e] & 0x7fffu) << 1);
    for (int off = 32; off; off >>= 1) s += __shfl_down(s, off);
    if (l == 0) dis[n] = rsqrtf(1.0f + s);
}

// --- 6. pull aggregation: one wave per node, 2 dims/lane, bf16 gathers, no atomics ---
__global__ __launch_bounds__(256) void pull_kernel(const unsigned int* __restrict__ xh,
        const float* __restrict__ dis, const int* __restrict__ row_ptr,
        const unsigned int* __restrict__ csr, float2* __restrict__ out2) {
    int t = blockIdx.x * 256 + threadIdx.x;
    int n = t >> 6, l = t & 63;
    float dn = dis[n], ss = dn * dn;
    unsigned int a = xh[n * 64 + l];
    float accx = bf2f(a & 0xffffu) * ss;             // self-loop term
    float accy = bf2f(a >> 16) * ss;
    int beg = row_ptr[n], end = row_ptr[n + 1];
    int e = beg;
    for (; e + 1 < end; e += 2) {
        unsigned int c0 = csr[e], c1 = csr[e + 1];
        int s0 = c0 >> 15, s1 = c1 >> 15;
        float n0 = dis[s0] * bf2f((c0 & 0x7fffu) << 1) * dn;
        float n1 = dis[s1] * bf2f((c1 & 0x7fffu) << 1) * dn;
        unsigned int u0 = xh[s0 * 64 + l];
        unsigned int u1 = xh[s1 * 64 + l];
        accx += bf2f(u0 & 0xffffu) * n0; accy += bf2f(u0 >> 16) * n0;
        accx += bf2f(u1 & 0xffffu) * n1; accy += bf2f(u1 >> 16) * n1;
    }
    if (e < end) {
        unsigned int c0 = csr[e];
        int s0 = c0 >> 15;
        float n0 = dis[s0] * bf2f((c0 & 0x7fffu) << 1) * dn;
        unsigned int u0 = xh[s0 * 64 + l];
        accx += bf2f(u0 & 0xffffu) * n0; accy += bf2f(u0 >> 16) * n0;
    }
    float2 r; r.x = accx; r.y = accy;
    out2[n * 64 + l] = r;
}

// --- 7. out = out @ W + b  IN-PLACE; 16 rows/block staged in LDS first ---
__global__ __launch_bounds__(256) void gemm_kernel(float* __restrict__ io,
        const float* __restrict__ W, const float* __restrict__ bias) {
    __shared__ float A[16][D + 1];
    int t = threadIdx.x;
    long base = (long)blockIdx.x * 16;
    const float4* Ag = (const float4*)(io + base * D);
#pragma unroll
    for (int i = 0; i < 2; i++) {
        int idx = t + 256 * i;
        float4 v = Ag[idx];
        int r = idx >> 5, c = (idx & 31) << 2;
        A[r][c] = v.x; A[r][c + 1] = v.y; A[r][c + 2] = v.z; A[r][c + 3] = v.w;
    }
    __syncthreads();
    int r = t >> 4, cg = t & 15;
    float c[8];
#pragma unroll
    for (int j = 0; j < 8; j++) c[j] = 0.f;
    const float4* W4 = (const float4*)W;
#pragma unroll 4
    for (int k = 0; k < D; k++) {
        float a = A[r][k];
        float4 w0 = W4[k * 32 + cg * 2];
        float4 w1 = W4[k * 32 + cg * 2 + 1];
        c[0] += a * w0.x; c[1] += a * w0.y; c[2] += a * w0.z; c[3] += a * w0.w;
        c[4] += a * w1.x; c[5] += a * w1.y; c[6] += a * w1.z; c[7] += a * w1.w;
    }
    long row = base + r;
    float4 o0, o1;
    const float* bp = bias + cg * 8;
    o0.x = c[0] + bp[0]; o0.y = c[1] + bp[1]; o0.z = c[2] + bp[2]; o0.w = c[3] + bp[3];
    o1.x = c[4] + bp[4]; o1.y = c[5] + bp[5]; o1.z = c[6] + bp[6]; o1.w = c[7] + bp[7];
    float4* op = (float4*)(io + row * D) + cg * 2;
    op[0] = o0; op[1] = o1;
}

extern "C" void kernel_launch(void* const* d_in, const int* in_sizes, int n_in,
                              void* d_out, int out_size, void* d_ws, size_t ws_size,
                              hipStream_t stream) {
    const float* x  = (const float*)d_in[0];
    const int*   ei = (const int*)d_in[1];
    const float* ew = (const float*)d_in[2];
    const float* W  = (const float*)d_in[3];
    const float* b  = (const float*)d_in[4];
    float* out = (float*)d_out;

    // workspace (~40 MB)
    float*        dis     = (float*)d_ws;                    // NN
    int*          cnt     = (int*)(dis + NN);                // NN
    int*          row_ptr = cnt + NN;                        // NN+1
    int*          fill    = row_ptr + NN + 1;                // NN
    int*          flag    = fill + NN;                       // 1
    unsigned int* xh      = (unsigned int*)(((uintptr_t)(flag + 1) + 15) & ~(uintptr_t)15); // NN*64
    unsigned int* csr     = xh + (size_t)NN * 64;            // NE

    detect_kernel<<<1, 64, 0, stream>>>(ei, flag);
    hipMemsetAsync(cnt, 0, NN * sizeof(int), stream);
    xhalf_kernel<<<(NN * 64) / 256, 256, 0, stream>>>((const float2*)x, xh);
    hist_kernel<<<(NE + 255) / 256, 256, 0, stream>>>(ei, cnt, flag);
    scan_kernel<<<1, 1024, 0, stream>>>(cnt, row_ptr, fill);
    fill_kernel<<<(NE + 255) / 256, 256, 0, stream>>>(ei, ew, fill, csr, flag);
    disr_kernel<<<NN / 4, 256, 0, stream>>>(row_ptr, csr, dis);
    pull_kernel<<<(NN * 64) / 256, 256, 0, stream>>>(xh, dis, row_ptr, csr, (float2*)out);
    gemm_kernel<<<NN / 16, 256, 0, stream>>>(out, W, b);
}

// Round 5
// 738.668 us; speedup vs baseline: 4.1589x; 1.4272x over previous
//
#include <hip/hip_runtime.h>

#define NN 100000
#define NE 3200000
#define D  128
#define NB ((NN + 255) / 256)   // 391 scan blocks

__device__ __forceinline__ float bf2f(unsigned int u) {      // u = bf16 bits
    union { unsigned int i; float f; } v; v.i = u << 16; return v.f;
}
__device__ __forceinline__ unsigned int f2bf(float f) {      // RNE
    union { float f; unsigned int i; } v; v.f = f;
    unsigned int u = v.i;
    return (u + 0x7fffu + ((u >> 16) & 1u)) >> 16;
}

// --- 0. detect edge_index element width: int64 -> odd int32 slots (high words) all zero ---
__global__ void detect_kernel(const int* __restrict__ ei, int* __restrict__ flag) {
    int t = threadIdx.x;
    int v = ei[2 * t + 1];
    unsigned long long ball = __ballot(v != 0);
    if (t == 0) flag[0] = (ball == 0ull) ? 1 : 0;   // 1 => int64
}

// --- 1. x -> packed bf16x2 copy (halves gather bytes in pull) ---
__global__ void xhalf_kernel(const float2* __restrict__ x2, unsigned int* __restrict__ xh) {
    int i = blockIdx.x * 256 + threadIdx.x;          // NN*64 exactly
    float2 v = x2[i];
    xh[i] = f2bf(v.x) | (f2bf(v.y) << 16);
}

// --- 2. count per dst; atomic RETURN VALUE = edge's within-bucket rank (saved, reused by fill) ---
__global__ void hist_kernel(const int* __restrict__ ei, int* __restrict__ cnt,
                            unsigned short* __restrict__ rnk, const int* __restrict__ flag) {
    int s = flag[0];
    int e = blockIdx.x * 256 + threadIdx.x;
    if (e < NE) {
        int r = atomicAdd(&cnt[ei[(NE + e) << s]], 1);
        rnk[e] = (unsigned short)r;                  // max in-degree ~70 << 65536
    }
}

// --- 3a. per-block partial sums of cnt ---
__global__ __launch_bounds__(256) void scan1_kernel(const int* __restrict__ cnt,
                                                    int* __restrict__ part) {
    __shared__ int red[256];
    int t = threadIdx.x, i = blockIdx.x * 256 + t;
    red[t] = (i < NN) ? cnt[i] : 0;
    __syncthreads();
    for (int off = 128; off; off >>= 1) {
        if (t < off) red[t] += red[t + off];
        __syncthreads();
    }
    if (t == 0) part[blockIdx.x] = red[0];
}

// --- 3b. exclusive scan of the 391 partials, one block ---
__global__ __launch_bounds__(512) void scan2_kernel(int* __restrict__ part) {
    __shared__ int s[512];
    int t = threadIdx.x;
    s[t] = (t < NB) ? part[t] : 0;
    __syncthreads();
    for (int off = 1; off < 512; off <<= 1) {
        int v = (t >= off) ? s[t - off] : 0;
        __syncthreads();
        s[t] += v;
        __syncthreads();
    }
    if (t < NB) part[t] = (t > 0) ? s[t - 1] : 0;
}

// --- 3c. block-local exclusive scan + base -> row_ptr ---
__global__ __launch_bounds__(256) void scan3_kernel(const int* __restrict__ cnt,
        const int* __restrict__ part, int* __restrict__ row_ptr) {
    __shared__ int s[256];
    int t = threadIdx.x, i = blockIdx.x * 256 + t;
    int v = (i < NN) ? cnt[i] : 0;
    s[t] = v;
    __syncthreads();
    for (int off = 1; off < 256; off <<= 1) {
        int u = (t >= off) ? s[t - off] : 0;
        __syncthreads();
        s[t] += u;
        __syncthreads();
    }
    int base = part[blockIdx.x];
    if (i < NN) row_ptr[i] = base + s[t] - v;
    if (i == NN - 1) row_ptr[NN] = base + s[t];      // == NE
}

// --- 4. bucket fill, ATOMIC-FREE: pos = row_ptr[dst] + rnk[e]; one scattered 4B store ---
__global__ void fill_kernel(const int* __restrict__ ei, const float* __restrict__ ew,
                            const unsigned short* __restrict__ rnk,
                            const int* __restrict__ row_ptr, unsigned int* __restrict__ csr,
                            const int* __restrict__ flag) {
    int s = flag[0];
    int e = blockIdx.x * 256 + threadIdx.x;
    if (e < NE) {
        int src = ei[e << s];
        int dst = ei[(NE + e) << s];
        int pos = row_ptr[dst] + rnk[e];
        unsigned int wb = f2bf(ew[e]);               // ew >= 0: sign bit is 0
        csr[pos] = ((unsigned int)src << 15) | (wb >> 1);
    }
}

// --- 5. dis[n] = rsqrt(1 + sum_row ew) -- coalesced, atomic-free; one wave per node ---
__global__ __launch_bounds__(256) void disr_kernel(const int* __restrict__ row_ptr,
        const unsigned int* __restrict__ csr, float* __restrict__ dis) {
    int n = blockIdx.x * 4 + (threadIdx.x >> 6);
    int l = threadIdx.x & 63;
    int beg = row_ptr[n], end = row_ptr[n + 1];
    float s = 0.f;
    for (int e = beg + l; e < end; e += 64)
        s += bf2f((csr[e] & 0x7fffu) << 1);
    for (int off = 32; off; off >>= 1) s += __shfl_down(s, off);
    if (l == 0) dis[n] = rsqrtf(1.0f + s);
}

// --- 6. pull aggregation: one wave per node, 2 dims/lane, bf16 gathers, no atomics ---
__global__ __launch_bounds__(256) void pull_kernel(const unsigned int* __restrict__ xh,
        const float* __restrict__ dis, const int* __restrict__ row_ptr,
        const unsigned int* __restrict__ csr, float2* __restrict__ out2) {
    int t = blockIdx.x * 256 + threadIdx.x;
    int n = t >> 6, l = t & 63;
    float dn = dis[n], ss = dn * dn;
    unsigned int a = xh[n * 64 + l];
    float accx = bf2f(a & 0xffffu) * ss;             // self-loop term
    float accy = bf2f(a >> 16) * ss;
    int beg = row_ptr[n], end = row_ptr[n + 1];
    int e = beg;
    for (; e + 1 < end; e += 2) {
        unsigned int c0 = csr[e], c1 = csr[e + 1];
        int s0 = c0 >> 15, s1 = c1 >> 15;
        float n0 = dis[s0] * bf2f((c0 & 0x7fffu) << 1) * dn;
        float n1 = dis[s1] * bf2f((c1 & 0x7fffu) << 1) * dn;
        unsigned int u0 = xh[s0 * 64 + l];
        unsigned int u1 = xh[s1 * 64 + l];
        accx += bf2f(u0 & 0xffffu) * n0; accy += bf2f(u0 >> 16) * n0;
        accx += bf2f(u1 & 0xffffu) * n1; accy += bf2f(u1 >> 16) * n1;
    }
    if (e < end) {
        unsigned int c0 = csr[e];
        int s0 = c0 >> 15;
        float n0 = dis[s0] * bf2f((c0 & 0x7fffu) << 1) * dn;
        unsigned int u0 = xh[s0 * 64 + l];
        accx += bf2f(u0 & 0xffffu) * n0; accy += bf2f(u0 >> 16) * n0;
    }
    float2 r; r.x = accx; r.y = accy;
    out2[n * 64 + l] = r;
}

// --- 7. out = out @ W + b  IN-PLACE; 16 rows/block staged in LDS first ---
__global__ __launch_bounds__(256) void gemm_kernel(float* __restrict__ io,
        const float* __restrict__ W, const float* __restrict__ bias) {
    __shared__ float A[16][D + 1];
    int t = threadIdx.x;
    long base = (long)blockIdx.x * 16;
    const float4* Ag = (const float4*)(io + base * D);
#pragma unroll
    for (int i = 0; i < 2; i++) {
        int idx = t + 256 * i;
        float4 v = Ag[idx];
        int r = idx >> 5, c = (idx & 31) << 2;
        A[r][c] = v.x; A[r][c + 1] = v.y; A[r][c + 2] = v.z; A[r][c + 3] = v.w;
    }
    __syncthreads();
    int r = t >> 4, cg = t & 15;
    float c[8];
#pragma unroll
    for (int j = 0; j < 8; j++) c[j] = 0.f;
    const float4* W4 = (const float4*)W;
#pragma unroll 4
    for (int k = 0; k < D; k++) {
        float a = A[r][k];
        float4 w0 = W4[k * 32 + cg * 2];
        float4 w1 = W4[k * 32 + cg * 2 + 1];
        c[0] += a * w0.x; c[1] += a * w0.y; c[2] += a * w0.z; c[3] += a * w0.w;
        c[4] += a * w1.x; c[5] += a * w1.y; c[6] += a * w1.z; c[7] += a * w1.w;
    }
    long row = base + r;
    float4 o0, o1;
    const float* bp = bias + cg * 8;
    o0.x = c[0] + bp[0]; o0.y = c[1] + bp[1]; o0.z = c[2] + bp[2]; o0.w = c[3] + bp[3];
    o1.x = c[4] + bp[4]; o1.y = c[5] + bp[5]; o1.z = c[6] + bp[6]; o1.w = c[7] + bp[7];
    float4* op = (float4*)(io + row * D) + cg * 2;
    op[0] = o0; op[1] = o1;
}

extern "C" void kernel_launch(void* const* d_in, const int* in_sizes, int n_in,
                              void* d_out, int out_size, void* d_ws, size_t ws_size,
                              hipStream_t stream) {
    const float* x  = (const float*)d_in[0];
    const int*   ei = (const int*)d_in[1];
    const float* ew = (const float*)d_in[2];
    const float* W  = (const float*)d_in[3];
    const float* b  = (const float*)d_in[4];
    float* out = (float*)d_out;

    // workspace (~46 MB)
    float*          dis     = (float*)d_ws;                    // NN
    int*            cnt     = (int*)(dis + NN);                // NN
    int*            row_ptr = cnt + NN;                        // NN+1
    int*            part    = row_ptr + NN + 1;                // 512
    int*            flag    = part + 512;                      // 1
    unsigned short* rnk     = (unsigned short*)(((uintptr_t)(flag + 1) + 15) & ~(uintptr_t)15); // NE u16
    unsigned int*   xh      = (unsigned int*)(rnk + NE);       // NN*64
    unsigned int*   csr     = xh + (size_t)NN * 64;            // NE

    detect_kernel<<<1, 64, 0, stream>>>(ei, flag);
    hipMemsetAsync(cnt, 0, NN * sizeof(int), stream);
    xhalf_kernel<<<(NN * 64) / 256, 256, 0, stream>>>((const float2*)x, xh);
    hist_kernel<<<(NE + 255) / 256, 256, 0, stream>>>(ei, cnt, rnk, flag);
    scan1_kernel<<<NB, 256, 0, stream>>>(cnt, part);
    scan2_kernel<<<1, 512, 0, stream>>>(part);
    scan3_kernel<<<NB, 256, 0, stream>>>(cnt, part, row_ptr);
    fill_kernel<<<(NE + 255) / 256, 256, 0, stream>>>(ei, ew, rnk, row_ptr, csr, flag);
    disr_kernel<<<NN / 4, 256, 0, stream>>>(row_ptr, csr, dis);
    pull_kernel<<<(NN * 64) / 256, 256, 0, stream>>>(xh, dis, row_ptr, csr, (float2*)out);
    gemm_kernel<<<NN / 16, 256, 0, stream>>>(out, W, b);
}

// Round 6
// 556.317 us; speedup vs baseline: 5.5221x; 1.3278x over previous
//
#include <hip/hip_runtime.h>

#define NN 100000
#define NE 3200000
#define D  128
#define NB ((NN + 255) / 256)   // 391 scan blocks

typedef __attribute__((ext_vector_type(8))) short bf16x8;
typedef __attribute__((ext_vector_type(4))) float f32x4;

__device__ __forceinline__ float bf2f(unsigned int u) {      // u = bf16 bits
    union { unsigned int i; float f; } v; v.i = u << 16; return v.f;
}
__device__ __forceinline__ unsigned int f2bf(float f) {      // RNE
    union { float f; unsigned int i; } v; v.f = f;
    unsigned int u = v.i;
    return (u + 0x7fffu + ((u >> 16) & 1u)) >> 16;
}

// --- 0. detect edge_index element width: int64 -> odd int32 slots (high words) all zero ---
__global__ void detect_kernel(const int* __restrict__ ei, int* __restrict__ flag) {
    int t = threadIdx.x;
    int v = ei[2 * t + 1];
    unsigned long long ball = __ballot(v != 0);
    if (t == 0) flag[0] = (ball == 0ull) ? 1 : 0;   // 1 => int64
}

// --- 1. h = bf16(x @ W): MFMA 16x16x32_bf16, 128 rows/block, 4 waves ---
// WT layout: [k>>3][n][8] bf16 -> K-loop B-frag = one contiguous 16B LDS read (2-way, free)
__global__ __launch_bounds__(256) void mgemm_kernel(const float* __restrict__ x,
        const float* __restrict__ W, unsigned short* __restrict__ hb) {
    __shared__ unsigned short WT[16 * 128 * 8];    // 32 KB
    int t = threadIdx.x;
    {
        int n = t & 127, half = t >> 7;
        for (int it = 0; it < 8; ++it) {
            int kb = half * 8 + it;                // k-chunk 0..15
            union { unsigned short s[8]; uint4 v; } pk;
#pragma unroll
            for (int j = 0; j < 8; ++j)
                pk.s[j] = (unsigned short)f2bf(W[(kb * 8 + j) * D + n]);
            *(uint4*)&WT[(kb * 128 + n) * 8] = pk.v;
        }
    }
    __syncthreads();
    int l = t & 63, w = t >> 6;
    int q = l >> 4, m = l & 15;
    long mbase = (long)blockIdx.x * 128 + w * 32;
    long r0 = mbase + m;      if (r0 > NN - 1) r0 = NN - 1;   // clamp: no OOB reads
    long r1 = mbase + 16 + m; if (r1 > NN - 1) r1 = NN - 1;
    const float* a0p = x + r0 * D + q * 8;
    const float* a1p = x + r1 * D + q * 8;
    f32x4 acc[2][8];
#pragma unroll
    for (int mt = 0; mt < 2; ++mt)
#pragma unroll
        for (int nt = 0; nt < 8; ++nt) acc[mt][nt] = (f32x4){0.f, 0.f, 0.f, 0.f};
#pragma unroll
    for (int kc = 0; kc < 4; ++kc) {
        float4 va0 = *(const float4*)(a0p + kc * 32);
        float4 va1 = *(const float4*)(a0p + kc * 32 + 4);
        float4 vb0 = *(const float4*)(a1p + kc * 32);
        float4 vb1 = *(const float4*)(a1p + kc * 32 + 4);
        union { unsigned short s[8]; bf16x8 v; } ua, ub;
        ua.s[0] = (unsigned short)f2bf(va0.x); ua.s[1] = (unsigned short)f2bf(va0.y);
        ua.s[2] = (unsigned short)f2bf(va0.z); ua.s[3] = (unsigned short)f2bf(va0.w);
        ua.s[4] = (unsigned short)f2bf(va1.x); ua.s[5] = (unsigned short)f2bf(va1.y);
        ua.s[6] = (unsigned short)f2bf(va1.z); ua.s[7] = (unsigned short)f2bf(va1.w);
        ub.s[0] = (unsigned short)f2bf(vb0.x); ub.s[1] = (unsigned short)f2bf(vb0.y);
        ub.s[2] = (unsigned short)f2bf(vb0.z); ub.s[3] = (unsigned short)f2bf(vb0.w);
        ub.s[4] = (unsigned short)f2bf(vb1.x); ub.s[5] = (unsigned short)f2bf(vb1.y);
        ub.s[6] = (unsigned short)f2bf(vb1.z); ub.s[7] = (unsigned short)f2bf(vb1.w);
        const bf16x8* bp = (const bf16x8*)WT + (kc * 4 + q) * 128 + m;
#pragma unroll
        for (int nt = 0; nt < 8; ++nt) {
            bf16x8 bfr = bp[nt * 16];
            acc[0][nt] = __builtin_amdgcn_mfma_f32_16x16x32_bf16(ua.v, bfr, acc[0][nt], 0, 0, 0);
            acc[1][nt] = __builtin_amdgcn_mfma_f32_16x16x32_bf16(ub.v, bfr, acc[1][nt], 0, 0, 0);
        }
    }
#pragma unroll
    for (int mt = 0; mt < 2; ++mt) {
        long rowbase = mbase + mt * 16;
#pragma unroll
        for (int nt = 0; nt < 8; ++nt)
#pragma unroll
            for (int r = 0; r < 4; ++r) {
                long row = rowbase + q * 4 + r;      // C/D: col=lane&15, row=quad*4+reg
                if (row < NN)
                    hb[row * D + nt * 16 + m] = (unsigned short)f2bf(acc[mt][nt][r]);
            }
    }
}

// --- 2. count per dst; atomic RETURN VALUE = within-bucket rank (reused by fill) ---
__global__ void hist_kernel(const int* __restrict__ ei, int* __restrict__ cnt,
                            unsigned short* __restrict__ rnk, const int* __restrict__ flag) {
    int s = flag[0];
    int e = blockIdx.x * 256 + threadIdx.x;
    if (e < NE) {
        int r = atomicAdd(&cnt[ei[(NE + e) << s]], 1);
        rnk[e] = (unsigned short)r;
    }
}

// --- 3a/3b/3c. three-phase exclusive scan -> row_ptr ---
__global__ __launch_bounds__(256) void scan1_kernel(const int* __restrict__ cnt,
                                                    int* __restrict__ part) {
    __shared__ int red[256];
    int t = threadIdx.x, i = blockIdx.x * 256 + t;
    red[t] = (i < NN) ? cnt[i] : 0;
    __syncthreads();
    for (int off = 128; off; off >>= 1) {
        if (t < off) red[t] += red[t + off];
        __syncthreads();
    }
    if (t == 0) part[blockIdx.x] = red[0];
}
__global__ __launch_bounds__(512) void scan2_kernel(int* __restrict__ part) {
    __shared__ int s[512];
    int t = threadIdx.x;
    s[t] = (t < NB) ? part[t] : 0;
    __syncthreads();
    for (int off = 1; off < 512; off <<= 1) {
        int v = (t >= off) ? s[t - off] : 0;
        __syncthreads();
        s[t] += v;
        __syncthreads();
    }
    if (t < NB) part[t] = (t > 0) ? s[t - 1] : 0;
}
__global__ __launch_bounds__(256) void scan3_kernel(const int* __restrict__ cnt,
        const int* __restrict__ part, int* __restrict__ row_ptr) {
    __shared__ int s[256];
    int t = threadIdx.x, i = blockIdx.x * 256 + t;
    int v = (i < NN) ? cnt[i] : 0;
    s[t] = v;
    __syncthreads();
    for (int off = 1; off < 256; off <<= 1) {
        int u = (t >= off) ? s[t - off] : 0;
        __syncthreads();
        s[t] += u;
        __syncthreads();
    }
    int base = part[blockIdx.x];
    if (i < NN) row_ptr[i] = base + s[t] - v;
    if (i == NN - 1) row_ptr[NN] = base + s[t];
}

// --- 4. bucket fill, atomic-free: pos = row_ptr[dst] + rnk[e] ---
__global__ void fill_kernel(const int* __restrict__ ei, const float* __restrict__ ew,
                            const unsigned short* __restrict__ rnk,
                            const int* __restrict__ row_ptr, unsigned int* __restrict__ csr,
                            const int* __restrict__ flag) {
    int s = flag[0];
    int e = blockIdx.x * 256 + threadIdx.x;
    if (e < NE) {
        int src = ei[e << s];
        int dst = ei[(NE + e) << s];
        int pos = row_ptr[dst] + rnk[e];
        unsigned int wb = f2bf(ew[e]);               // ew >= 0: sign bit 0
        csr[pos] = ((unsigned int)src << 15) | (wb >> 1);
    }
}

// --- 5. dis[n] = rsqrt(1 + sum_row ew) -- coalesced, atomic-free ---
__global__ __launch_bounds__(256) void disr_kernel(const int* __restrict__ row_ptr,
        const unsigned int* __restrict__ csr, float* __restrict__ dis) {
    int n = blockIdx.x * 4 + (threadIdx.x >> 6);
    int l = threadIdx.x & 63;
    int beg = row_ptr[n], end = row_ptr[n + 1];
    float s = 0.f;
    for (int e = beg + l; e < end; e += 64)
        s += bf2f((csr[e] & 0x7fffu) << 1);
    for (int off = 32; off; off >>= 1) s += __shfl_down(s, off);
    if (l == 0) dis[n] = rsqrtf(1.0f + s);
}

// --- 6. pull: out = Agg(h) + bias ; one wave per node, 2 dims/lane, bf16 gathers ---
__global__ __launch_bounds__(256) void pull_kernel(const unsigned int* __restrict__ hb,
        const float* __restrict__ dis, const int* __restrict__ row_ptr,
        const unsigned int* __restrict__ csr, const float2* __restrict__ bias2,
        float2* __restrict__ out2) {
    int t = blockIdx.x * 256 + threadIdx.x;
    int n = t >> 6, l = t & 63;
    float dn = dis[n], ss = dn * dn;
    unsigned int a = hb[n * 64 + l];
    float accx = bf2f(a & 0xffffu) * ss;             // self-loop term
    float accy = bf2f(a >> 16) * ss;
    int beg = row_ptr[n], end = row_ptr[n + 1];
    int e = beg;
    for (; e + 1 < end; e += 2) {
        unsigned int c0 = csr[e], c1 = csr[e + 1];
        int s0 = c0 >> 15, s1 = c1 >> 15;
        float n0 = dis[s0] * bf2f((c0 & 0x7fffu) << 1) * dn;
        float n1 = dis[s1] * bf2f((c1 & 0x7fffu) << 1) * dn;
        unsigned int u0 = hb[s0 * 64 + l];
        unsigned int u1 = hb[s1 * 64 + l];
        accx += bf2f(u0 & 0xffffu) * n0; accy += bf2f(u0 >> 16) * n0;
        accx += bf2f(u1 & 0xffffu) * n1; accy += bf2f(u1 >> 16) * n1;
    }
    if (e < end) {
        unsigned int c0 = csr[e];
        int s0 = c0 >> 15;
        float n0 = dis[s0] * bf2f((c0 & 0x7fffu) << 1) * dn;
        unsigned int u0 = hb[s0 * 64 + l];
        accx += bf2f(u0 & 0xffffu) * n0; accy += bf2f(u0 >> 16) * n0;
    }
    float2 bv = bias2[l];
    float2 r; r.x = accx + bv.x; r.y = accy + bv.y;
    out2[n * 64 + l] = r;
}

extern "C" void kernel_launch(void* const* d_in, const int* in_sizes, int n_in,
                              void* d_out, int out_size, void* d_ws, size_t ws_size,
                              hipStream_t stream) {
    const float* x  = (const float*)d_in[0];
    const int*   ei = (const int*)d_in[1];
    const float* ew = (const float*)d_in[2];
    const float* W  = (const float*)d_in[3];
    const float* b  = (const float*)d_in[4];
    float* out = (float*)d_out;

    // workspace (~46 MB)
    float*          dis     = (float*)d_ws;                    // NN
    int*            cnt     = (int*)(dis + NN);                // NN
    int*            row_ptr = cnt + NN;                        // NN+1
    int*            part    = row_ptr + NN + 1;                // 512
    int*            flag    = part + 512;                      // 1
    unsigned short* rnk     = (unsigned short*)(((uintptr_t)(flag + 1) + 15) & ~(uintptr_t)15); // NE u16
    unsigned int*   csr     = (unsigned int*)(rnk + NE);       // NE u32
    unsigned short* hb      = (unsigned short*)(csr + NE);     // NN*128 bf16 (25.6 MB)

    detect_kernel<<<1, 64, 0, stream>>>(ei, flag);
    hipMemsetAsync(cnt, 0, NN * sizeof(int), stream);
    mgemm_kernel<<<(NN + 127) / 128, 256, 0, stream>>>(x, W, hb);
    hist_kernel<<<(NE + 255) / 256, 256, 0, stream>>>(ei, cnt, rnk, flag);
    scan1_kernel<<<NB, 256, 0, stream>>>(cnt, part);
    scan2_kernel<<<1, 512, 0, stream>>>(part);
    scan3_kernel<<<NB, 256, 0, stream>>>(cnt, part, row_ptr);
    fill_kernel<<<(NE + 255) / 256, 256, 0, stream>>>(ei, ew, rnk, row_ptr, csr, flag);
    disr_kernel<<<NN / 4, 256, 0, stream>>>(row_ptr, csr, dis);
    pull_kernel<<<(NN * 64) / 256, 256, 0, stream>>>((const unsigned int*)hb, dis, row_ptr, csr,
                                                     (const float2*)b, (float2*)out);
}

// Round 7
// 522.146 us; speedup vs baseline: 5.8835x; 1.0654x over previous
//
#include <hip/hip_runtime.h>

#define NN 100000
#define NE 3200000
#define D  128
#define NB ((NN + 255) / 256)   // 391 scan blocks

typedef __attribute__((ext_vector_type(8))) short bf16x8;
typedef __attribute__((ext_vector_type(4))) float f32x4;

__device__ __forceinline__ float bf2f(unsigned int u) {      // u = bf16 bits
    union { unsigned int i; float f; } v; v.i = u << 16; return v.f;
}
__device__ __forceinline__ unsigned int f2bf(float f) {      // RNE
    union { float f; unsigned int i; } v; v.f = f;
    unsigned int u = v.i;
    return (u + 0x7fffu + ((u >> 16) & 1u)) >> 16;
}

// --- 0. detect edge_index element width: int64 -> odd int32 slots (high words) all zero ---
__global__ void detect_kernel(const int* __restrict__ ei, int* __restrict__ flag) {
    int t = threadIdx.x;
    int v = ei[2 * t + 1];
    unsigned long long ball = __ballot(v != 0);
    if (t == 0) flag[0] = (ball == 0ull) ? 1 : 0;   // 1 => int64
}

// --- 1. h = bf16(x @ W): MFMA 16x16x32_bf16, 128 rows/block, 4 waves ---
__global__ __launch_bounds__(256) void mgemm_kernel(const float* __restrict__ x,
        const float* __restrict__ W, unsigned short* __restrict__ hb) {
    __shared__ unsigned short WT[16 * 128 * 8];    // 32 KB
    int t = threadIdx.x;
    {
        int n = t & 127, half = t >> 7;
        for (int it = 0; it < 8; ++it) {
            int kb = half * 8 + it;                // k-chunk 0..15
            union { unsigned short s[8]; uint4 v; } pk;
#pragma unroll
            for (int j = 0; j < 8; ++j)
                pk.s[j] = (unsigned short)f2bf(W[(kb * 8 + j) * D + n]);
            *(uint4*)&WT[(kb * 128 + n) * 8] = pk.v;
        }
    }
    __syncthreads();
    int l = t & 63, w = t >> 6;
    int q = l >> 4, m = l & 15;
    long mbase = (long)blockIdx.x * 128 + w * 32;
    long r0 = mbase + m;      if (r0 > NN - 1) r0 = NN - 1;   // clamp: no OOB reads
    long r1 = mbase + 16 + m; if (r1 > NN - 1) r1 = NN - 1;
    const float* a0p = x + r0 * D + q * 8;
    const float* a1p = x + r1 * D + q * 8;
    f32x4 acc[2][8];
#pragma unroll
    for (int mt = 0; mt < 2; ++mt)
#pragma unroll
        for (int nt = 0; nt < 8; ++nt) acc[mt][nt] = (f32x4){0.f, 0.f, 0.f, 0.f};
#pragma unroll
    for (int kc = 0; kc < 4; ++kc) {
        float4 va0 = *(const float4*)(a0p + kc * 32);
        float4 va1 = *(const float4*)(a0p + kc * 32 + 4);
        float4 vb0 = *(const float4*)(a1p + kc * 32);
        float4 vb1 = *(const float4*)(a1p + kc * 32 + 4);
        union { unsigned short s[8]; bf16x8 v; } ua, ub;
        ua.s[0] = (unsigned short)f2bf(va0.x); ua.s[1] = (unsigned short)f2bf(va0.y);
        ua.s[2] = (unsigned short)f2bf(va0.z); ua.s[3] = (unsigned short)f2bf(va0.w);
        ua.s[4] = (unsigned short)f2bf(va1.x); ua.s[5] = (unsigned short)f2bf(va1.y);
        ua.s[6] = (unsigned short)f2bf(va1.z); ua.s[7] = (unsigned short)f2bf(va1.w);
        ub.s[0] = (unsigned short)f2bf(vb0.x); ub.s[1] = (unsigned short)f2bf(vb0.y);
        ub.s[2] = (unsigned short)f2bf(vb0.z); ub.s[3] = (unsigned short)f2bf(vb0.w);
        ub.s[4] = (unsigned short)f2bf(vb1.x); ub.s[5] = (unsigned short)f2bf(vb1.y);
        ub.s[6] = (unsigned short)f2bf(vb1.z); ub.s[7] = (unsigned short)f2bf(vb1.w);
        const bf16x8* bp = (const bf16x8*)WT + (kc * 4 + q) * 128 + m;
#pragma unroll
        for (int nt = 0; nt < 8; ++nt) {
            bf16x8 bfr = bp[nt * 16];
            acc[0][nt] = __builtin_amdgcn_mfma_f32_16x16x32_bf16(ua.v, bfr, acc[0][nt], 0, 0, 0);
            acc[1][nt] = __builtin_amdgcn_mfma_f32_16x16x32_bf16(ub.v, bfr, acc[1][nt], 0, 0, 0);
        }
    }
#pragma unroll
    for (int mt = 0; mt < 2; ++mt) {
        long rowbase = mbase + mt * 16;
#pragma unroll
        for (int nt = 0; nt < 8; ++nt)
#pragma unroll
            for (int r = 0; r < 4; ++r) {
                long row = rowbase + q * 4 + r;      // C/D: col=lane&15, row=quad*4+reg
                if (row < NN)
                    hb[row * D + nt * 16 + m] = (unsigned short)f2bf(acc[mt][nt][r]);
            }
    }
}

// --- 2. count per dst; atomic RETURN VALUE = within-bucket rank (u8: max in-deg ~70) ---
__global__ void hist_kernel(const int* __restrict__ ei, int* __restrict__ cnt,
                            unsigned char* __restrict__ rnk, const int* __restrict__ flag) {
    int s = flag[0];
    int e = blockIdx.x * 256 + threadIdx.x;
    if (e < NE) {
        int r = atomicAdd(&cnt[ei[(NE + e) << s]], 1);
        rnk[e] = (unsigned char)r;
    }
}

// --- 3a/3b/3c. three-phase exclusive scan -> row_ptr ---
__global__ __launch_bounds__(256) void scan1_kernel(const int* __restrict__ cnt,
                                                    int* __restrict__ part) {
    __shared__ int red[256];
    int t = threadIdx.x, i = blockIdx.x * 256 + t;
    red[t] = (i < NN) ? cnt[i] : 0;
    __syncthreads();
    for (int off = 128; off; off >>= 1) {
        if (t < off) red[t] += red[t + off];
        __syncthreads();
    }
    if (t == 0) part[blockIdx.x] = red[0];
}
__global__ __launch_bounds__(512) void scan2_kernel(int* __restrict__ part) {
    __shared__ int s[512];
    int t = threadIdx.x;
    s[t] = (t < NB) ? part[t] : 0;
    __syncthreads();
    for (int off = 1; off < 512; off <<= 1) {
        int v = (t >= off) ? s[t - off] : 0;
        __syncthreads();
        s[t] += v;
        __syncthreads();
    }
    if (t < NB) part[t] = (t > 0) ? s[t - 1] : 0;
}
__global__ __launch_bounds__(256) void scan3_kernel(const int* __restrict__ cnt,
        const int* __restrict__ part, int* __restrict__ row_ptr) {
    __shared__ int s[256];
    int t = threadIdx.x, i = blockIdx.x * 256 + t;
    int v = (i < NN) ? cnt[i] : 0;
    s[t] = v;
    __syncthreads();
    for (int off = 1; off < 256; off <<= 1) {
        int u = (t >= off) ? s[t - off] : 0;
        __syncthreads();
        s[t] += u;
        __syncthreads();
    }
    int base = part[blockIdx.x];
    if (i < NN) row_ptr[i] = base + s[t] - v;
    if (i == NN - 1) row_ptr[NN] = base + s[t];
}

// --- 4. bucket fill, atomic-free: pos = row_ptr[dst] + rnk[e] ---
__global__ void fill_kernel(const int* __restrict__ ei, const float* __restrict__ ew,
                            const unsigned char* __restrict__ rnk,
                            const int* __restrict__ row_ptr, unsigned int* __restrict__ csr,
                            const int* __restrict__ flag) {
    int s = flag[0];
    int e = blockIdx.x * 256 + threadIdx.x;
    if (e < NE) {
        int src = ei[e << s];
        int dst = ei[(NE + e) << s];
        int pos = row_ptr[dst] + rnk[e];
        unsigned int wb = f2bf(ew[e]);               // ew >= 0: sign bit 0
        csr[pos] = ((unsigned int)src << 15) | (wb >> 1);
    }
}

// --- 5. dis[n] = rsqrt(1 + sum_row ew) -- coalesced, atomic-free ---
__global__ __launch_bounds__(256) void disr_kernel(const int* __restrict__ row_ptr,
        const unsigned int* __restrict__ csr, float* __restrict__ dis) {
    int n = blockIdx.x * 4 + (threadIdx.x >> 6);
    int l = threadIdx.x & 63;
    int beg = row_ptr[n], end = row_ptr[n + 1];
    float s = 0.f;
    for (int e = beg + l; e < end; e += 64)
        s += bf2f((csr[e] & 0x7fffu) << 1);
    for (int off = 32; off; off >>= 1) s += __shfl_down(s, off);
    if (l == 0) dis[n] = rsqrtf(1.0f + s);
}

// --- 6. pull: out = Agg(h) + bias ; one wave/node, 8 gathers in flight (MLP) ---
__global__ __launch_bounds__(256) void pull_kernel(const unsigned int* __restrict__ hb,
        const float* __restrict__ dis, const int* __restrict__ row_ptr,
        const unsigned int* __restrict__ csr, const float2* __restrict__ bias2,
        float2* __restrict__ out2) {
    int t = blockIdx.x * 256 + threadIdx.x;
    int n = t >> 6, l = t & 63;
    float dn = dis[n], ss = dn * dn;
    unsigned int a = hb[n * 64 + l];
    float accx = bf2f(a & 0xffffu) * ss;             // self-loop term
    float accy = bf2f(a >> 16) * ss;
    int beg = row_ptr[n], end = row_ptr[n + 1];
    int e = beg;
    for (; e + 7 < end; e += 8) {                    // 8 independent row-gathers in flight
        unsigned int c[8];
#pragma unroll
        for (int j = 0; j < 8; ++j) c[j] = csr[e + j];   // wave-uniform -> scalar loads
        int s_[8];
#pragma unroll
        for (int j = 0; j < 8; ++j) s_[j] = c[j] >> 15;
        unsigned int u[8];
#pragma unroll
        for (int j = 0; j < 8; ++j) u[j] = hb[s_[j] * 64 + l];
#pragma unroll
        for (int j = 0; j < 8; ++j) {
            float nw = dis[s_[j]] * bf2f((c[j] & 0x7fffu) << 1) * dn;
            accx += bf2f(u[j] & 0xffffu) * nw;
            accy += bf2f(u[j] >> 16) * nw;
        }
    }
    for (; e + 1 < end; e += 2) {
        unsigned int c0 = csr[e], c1 = csr[e + 1];
        int s0 = c0 >> 15, s1 = c1 >> 15;
        float n0 = dis[s0] * bf2f((c0 & 0x7fffu) << 1) * dn;
        float n1 = dis[s1] * bf2f((c1 & 0x7fffu) << 1) * dn;
        unsigned int u0 = hb[s0 * 64 + l];
        unsigned int u1 = hb[s1 * 64 + l];
        accx += bf2f(u0 & 0xffffu) * n0; accy += bf2f(u0 >> 16) * n0;
        accx += bf2f(u1 & 0xffffu) * n1; accy += bf2f(u1 >> 16) * n1;
    }
    if (e < end) {
        unsigned int c0 = csr[e];
        int s0 = c0 >> 15;
        float n0 = dis[s0] * bf2f((c0 & 0x7fffu) << 1) * dn;
        unsigned int u0 = hb[s0 * 64 + l];
        accx += bf2f(u0 & 0xffffu) * n0; accy += bf2f(u0 >> 16) * n0;
    }
    float2 bv = bias2[l];
    float2 r; r.x = accx + bv.x; r.y = accy + bv.y;
    out2[n * 64 + l] = r;
}

extern "C" void kernel_launch(void* const* d_in, const int* in_sizes, int n_in,
                              void* d_out, int out_size, void* d_ws, size_t ws_size,
                              hipStream_t stream) {
    const float* x  = (const float*)d_in[0];
    const int*   ei = (const int*)d_in[1];
    const float* ew = (const float*)d_in[2];
    const float* W  = (const float*)d_in[3];
    const float* b  = (const float*)d_in[4];
    float* out = (float*)d_out;

    // workspace (~43 MB)
    float*          dis     = (float*)d_ws;                    // NN
    int*            cnt     = (int*)(dis + NN);                // NN
    int*            row_ptr = cnt + NN;                        // NN+1
    int*            part    = row_ptr + NN + 1;                // 512
    int*            flag    = part + 512;                      // 1
    unsigned char*  rnk     = (unsigned char*)(((uintptr_t)(flag + 1) + 15) & ~(uintptr_t)15); // NE u8
    unsigned int*   csr     = (unsigned int*)(rnk + NE);       // NE u32
    unsigned short* hb      = (unsigned short*)(csr + NE);     // NN*128 bf16 (25.6 MB)

    detect_kernel<<<1, 64, 0, stream>>>(ei, flag);
    hipMemsetAsync(cnt, 0, NN * sizeof(int), stream);
    mgemm_kernel<<<(NN + 127) / 128, 256, 0, stream>>>(x, W, hb);
    hist_kernel<<<(NE + 255) / 256, 256, 0, stream>>>(ei, cnt, rnk, flag);
    scan1_kernel<<<NB, 256, 0, stream>>>(cnt, part);
    scan2_kernel<<<1, 512, 0, stream>>>(part);
    scan3_kernel<<<NB, 256, 0, stream>>>(cnt, part, row_ptr);
    fill_kernel<<<(NE + 255) / 256, 256, 0, stream>>>(ei, ew, rnk, row_ptr, csr, flag);
    disr_kernel<<<NN / 4, 256, 0, stream>>>(row_ptr, csr, dis);
    pull_kernel<<<(NN * 64) / 256, 256, 0, stream>>>((const unsigned int*)hb, dis, row_ptr, csr,
                                                     (const float2*)b, (float2*)out);
}